// Round 1
// baseline (1206.792 us; speedup 1.0000x reference)
//
#include <hip/hip_runtime.h>

// SLAYER constants
#define ALPHA  0.90483741803595952f   /* exp(-1/10) */
#define ALPHA8 0.44932896411722156f   /* exp(-0.8)  */
#define THETA  10.0f

// ---------------------------------------------------------------------------
// Generic batched tiled GEMM (fp32):
//   C[b][m][n] = sum_k A[m][k] * Bel(b,k,n)
//   A shared across batch, row-major [M][K].
//   BT=false: Bel = Bbase[b*bStride + k*ldb + n]
//   BT=true : Bel = Bbase[b*bStride + n*ldb + k]
// 64x64 tile, BK=32, 256 threads, 4x4 micro-tile.
// ---------------------------------------------------------------------------
template <bool BT>
__global__ __launch_bounds__(256) void gemm_kernel(
    const float* __restrict__ A, const float* __restrict__ B,
    float* __restrict__ C, int M, int N, int K, int ldb,
    long long bStride, long long cStride)
{
    __shared__ float As[32][65];  // [k][m], pad to 65 (odd -> conflict-free)
    __shared__ float Bs[32][65];  // [k][n]

    const int b  = blockIdx.z;
    const int m0 = blockIdx.y * 64;
    const int n0 = blockIdx.x * 64;
    const float* Bb = B + (long long)b * bStride;
    float* Cb = C + (long long)b * cStride;

    const int tid = threadIdx.x;
    const int tx = tid & 15;       // n group
    const int ty = tid >> 4;       // m group

    float acc[4][4];
    #pragma unroll
    for (int i = 0; i < 4; ++i)
        #pragma unroll
        for (int j = 0; j < 4; ++j) acc[i][j] = 0.f;

    for (int k0 = 0; k0 < K; k0 += 32) {
        // ---- load A tile: 64 m x 32 k (coalesced along k) ----
        #pragma unroll
        for (int s = 0; s < 8; ++s) {
            int idx = tid + s * 256;
            int r = idx >> 5;          // m offset
            int c = idx & 31;          // k offset
            int m = m0 + r, k = k0 + c;
            float v = (m < M && k < K) ? A[(long long)m * K + k] : 0.f;
            As[c][r] = v;
        }
        // ---- load B tile: 32 k x 64 n ----
        if (!BT) {
            #pragma unroll
            for (int s = 0; s < 8; ++s) {
                int idx = tid + s * 256;
                int r = idx >> 6;      // k offset
                int c = idx & 63;      // n offset
                int k = k0 + r, n = n0 + c;
                float v = (k < K && n < N) ? Bb[(long long)k * ldb + n] : 0.f;
                Bs[r][c] = v;
            }
        } else {
            #pragma unroll
            for (int s = 0; s < 8; ++s) {
                int idx = tid + s * 256;
                int kk = idx & 31;     // k offset (coalesced along k)
                int c  = idx >> 5;     // n offset
                int k = k0 + kk, n = n0 + c;
                float v = (k < K && n < N) ? Bb[(long long)n * ldb + k] : 0.f;
                Bs[kk][c] = v;
            }
        }
        __syncthreads();

        #pragma unroll
        for (int kk = 0; kk < 32; ++kk) {
            float av[4], bv[4];
            #pragma unroll
            for (int i = 0; i < 4; ++i) av[i] = As[kk][ty * 4 + i];
            #pragma unroll
            for (int j = 0; j < 4; ++j) bv[j] = Bs[kk][tx * 4 + j];
            #pragma unroll
            for (int i = 0; i < 4; ++i)
                #pragma unroll
                for (int j = 0; j < 4; ++j) acc[i][j] += av[i] * bv[j];
        }
        __syncthreads();
    }

    #pragma unroll
    for (int i = 0; i < 4; ++i) {
        int m = m0 + ty * 4 + i;
        if (m >= M) continue;
        #pragma unroll
        for (int j = 0; j < 4; ++j) {
            int n = n0 + tx * 4 + j;
            if (n < N) Cb[(long long)m * N + n] = acc[i][j];
        }
    }
}

// ---------------------------------------------------------------------------
// Parallel alpha-scan + spike over T=2048 per row.
// One block (256 threads) per row; each thread scans 8 consecutive elements,
// carries combined with Kogge-Stone (weights alpha^(8d)).
// Writes spikes to out[row*out_stride + out_offset + t]. Safe in-place.
// ---------------------------------------------------------------------------
__global__ __launch_bounds__(256) void scan_spike_T(
    const float* __restrict__ in, float* __restrict__ out,
    int out_stride, int out_offset)
{
    const int row = blockIdx.x;
    const int tid = threadIdx.x;
    const float* x = in + (long long)row * 2048 + tid * 8;

    float v[8];
    #pragma unroll
    for (int k = 0; k < 8; ++k) v[k] = x[k];

    // local inclusive scan
    float y = 0.f;
    #pragma unroll
    for (int k = 0; k < 8; ++k) { y = ALPHA * y + v[k]; v[k] = y; }

    // block scan of chunk carries: c[j] = alpha^8 * c[j-1] + e[j]
    __shared__ float sc[256];
    float val = y;            // e_j
    sc[tid] = val;
    float m = ALPHA8;
    for (int d = 1; d < 256; d <<= 1) {
        __syncthreads();
        float p = (tid >= d) ? sc[tid - d] : 0.f;
        __syncthreads();
        val += m * p;
        sc[tid] = val;
        m *= m;
    }
    __syncthreads();
    float carry = (tid > 0) ? sc[tid - 1] : 0.f;

    float* o = out + (long long)row * out_stride + out_offset + tid * 8;
    float ak = ALPHA;
    #pragma unroll
    for (int k = 0; k < 8; ++k) {
        float yk = v[k] + ak * carry;
        ak *= ALPHA;
        o[k] = (yk >= THETA) ? 1.0f : 0.0f;
    }
}

// ---------------------------------------------------------------------------
// Branch-2 layer-1 scan: length-156 alpha-scan in perm order + spike.
// One thread per row. in: [rows][156] (original channel order),
// out: [rows][156] in permuted (scan) order.
// ---------------------------------------------------------------------------
__global__ __launch_bounds__(256) void scan_spike_C_perm(
    const float* __restrict__ in, const int* __restrict__ perm,
    float* __restrict__ out, int rows)
{
    __shared__ int p[156];
    for (int i = threadIdx.x; i < 156; i += blockDim.x) p[i] = perm[i];
    __syncthreads();

    int row = blockIdx.x * blockDim.x + threadIdx.x;
    if (row >= rows) return;
    const float* x = in + (long long)row * 156;
    float* o = out + (long long)row * 156;
    float y = 0.f;
    for (int c = 0; c < 156; ++c) {
        y = ALPHA * y + x[p[c]];
        o[c] = (y >= THETA) ? 1.0f : 0.0f;
    }
}

// ---------------------------------------------------------------------------
// Branch-2 layer-2 scan: length-156 alpha-scan + spike, writes to d_out at
// [row*2204 + 2048 + c]. One thread per row (rows = 640).
// ---------------------------------------------------------------------------
__global__ __launch_bounds__(256) void scan_spike_C_out(
    const float* __restrict__ in, float* __restrict__ out, int rows)
{
    int row = blockIdx.x * blockDim.x + threadIdx.x;
    if (row >= rows) return;
    const float* x = in + (long long)row * 156;
    float* o = out + (long long)row * 2204 + 2048;
    float y = 0.f;
    for (int c = 0; c < 156; ++c) {
        y = ALPHA * y + x[c];
        o[c] = (y >= THETA) ? 1.0f : 0.0f;
    }
}

// ---------------------------------------------------------------------------
// Dimensions: B=32, C_IN=156, T=2048, HID=512, OUT=20. Output [32,20,2204].
// ---------------------------------------------------------------------------
extern "C" void kernel_launch(void* const* d_in, const int* in_sizes, int n_in,
                              void* d_out, int out_size, void* d_ws, size_t ws_size,
                              hipStream_t stream)
{
    const float* In  = (const float*)d_in[0];  // [32][156][2048]
    const float* W1  = (const float*)d_in[1];  // [512][156]
    const float* W2  = (const float*)d_in[2];  // [20][512]
    const float* Wl1 = (const float*)d_in[3];  // [512][2048]
    const float* Wl2 = (const float*)d_in[4];  // [20][512]
    const int*  perm = (const int*)d_in[5];    // [156]
    float* out = (float*)d_out;                // [32][20][2204]

    float* ws  = (float*)d_ws;
    float* D1  = ws;                     // [32][512][2048] = 33,554,432 (reused in-place for s1)
    float* C2  = D1 + 33554432LL;        // [32][20][2048]  =  1,310,720
    float* Z   = C2 + 1310720LL;         // [32][512][156]  =  2,555,904
    float* L1  = Z  + 2555904LL;         // [32][512][156]  =  2,555,904
    float* Cl2 = L1 + 2555904LL;         // [32][20][156]   =     99,840
    // total 160.3 MB

    dim3 blk(256);

    // ---- Branch 1 ----
    // D1[b][h][t] = sum_c W1[h][c] * In[b][c][t]
    gemm_kernel<false><<<dim3(32, 8, 32), blk, 0, stream>>>(
        W1, In, D1, 512, 2048, 156, 2048, 156LL * 2048, 512LL * 2048);
    // s1 = spike(psp(D1)), in place
    scan_spike_T<<<dim3(16384), blk, 0, stream>>>(D1, D1, 2048, 0);
    // C2[b][o][t] = sum_h W2[o][h] * s1[b][h][t]
    gemm_kernel<false><<<dim3(32, 1, 32), blk, 0, stream>>>(
        W2, D1, C2, 20, 2048, 512, 2048, 512LL * 2048, 20LL * 2048);
    // spike_output -> out[..., 0:2048]
    scan_spike_T<<<dim3(640), blk, 0, stream>>>(C2, out, 2204, 0);

    // ---- Branch 2 ----
    // Z[b][h][c] = sum_t Wl1[h][t] * In[b][c][t]   (B transposed)
    gemm_kernel<true><<<dim3(3, 8, 32), blk, 0, stream>>>(
        Wl1, In, Z, 512, 156, 2048, 2048, 156LL * 2048, 512LL * 156);
    // L1[b][h][c] = spike(psp over c in perm order)
    scan_spike_C_perm<<<dim3(64), blk, 0, stream>>>(Z, perm, L1, 16384);
    // Cl2[b][o][c] = sum_h Wl2[o][h] * L1[b][h][c]
    gemm_kernel<false><<<dim3(3, 1, 32), blk, 0, stream>>>(
        Wl2, L1, Cl2, 20, 156, 512, 156, 512LL * 156, 20LL * 156);
    // location_output -> out[..., 2048:2204]
    scan_spike_C_out<<<dim3(3), blk, 0, stream>>>(Cl2, out, 640);

    (void)in_sizes; (void)n_in; (void)out_size; (void)ws_size;
}

// Round 2
// 564.579 us; speedup vs baseline: 2.1375x; 2.1375x over previous
//
#include <hip/hip_runtime.h>

// SLAYER constants
#define ALPHA  0.90483741803595952f   /* exp(-1/10) */
#define ALPHA8 0.44932896411722156f   /* exp(-0.8)  */
#define THETA  10.0f

typedef short   bf16x8 __attribute__((ext_vector_type(8)));
typedef float   f32x4  __attribute__((ext_vector_type(4)));

// RNE float -> bf16 bits
__device__ __forceinline__ unsigned short f2bf(float f) {
    unsigned int x = __float_as_uint(f);
    unsigned int r = (x + 0x7FFFu + ((x >> 16) & 1u)) >> 16;
    return (unsigned short)r;
}
__device__ __forceinline__ float bf2f(unsigned short h) {
    return __uint_as_float(((unsigned int)h) << 16);
}
// 3-way bf16 split of an fp32 weight: w ~= h0+h1+h2 (residual ~2^-26 * |w|)
__device__ __forceinline__ void split3(float w, unsigned short& h0,
                                       unsigned short& h1, unsigned short& h2) {
    h0 = f2bf(w);          float r0 = w - bf2f(h0);
    h1 = f2bf(r0);         float r1 = r0 - bf2f(h1);
    h2 = f2bf(r1);
}

// ---------------------------------------------------------------------------
// Branch-1 GEMM1 (MFMA, split-3 bf16):
//   D1[b][m][n] = sum_c W1[m][c] * In[b][c][n],  M=512, N=2048, K=156 (pad 160)
// Block tile 128x128, BK=32, 256 thr (4 waves, 2x2 of 64x64 wave tiles).
// ---------------------------------------------------------------------------
__global__ __launch_bounds__(256) void gemm1_mfma(
    const float* __restrict__ W1,   // [512][156]
    const float* __restrict__ In,   // [32][156][2048]
    float* __restrict__ D1)         // [32][512][2048]
{
    __shared__ alignas(16) unsigned short As[3][128][40]; // [split][m][k], pad 40
    __shared__ alignas(16) unsigned short Bs[128][40];    // [n][k]

    const int b  = blockIdx.z;
    const int m0 = blockIdx.y * 128;
    const int n0 = blockIdx.x * 128;
    const int tid  = threadIdx.x;
    const int lane = tid & 63, w = tid >> 6;
    const int wy = w >> 1, wx = w & 1;        // 2x2 wave grid
    const int l15 = lane & 15, kq = lane >> 4;

    const float* Inb = In + (long long)b * 156 * 2048;

    f32x4 acc[4][4] = {};

    for (int k0 = 0; k0 < 160; k0 += 32) {
        // ---- stage A (128m x 32k): thread -> row tid>>1, half-row (tid&1)*16
        {
            int m = tid >> 1, koff = (tid & 1) * 16;
            const float* src = W1 + (long long)(m0 + m) * 156;
            #pragma unroll
            for (int i = 0; i < 16; ++i) {
                int k = k0 + koff + i;
                float v = (k < 156) ? src[k] : 0.f;
                unsigned short h0, h1, h2;
                split3(v, h0, h1, h2);
                As[0][m][koff + i] = h0;
                As[1][m][koff + i] = h1;
                As[2][m][koff + i] = h2;
            }
        }
        // ---- stage B transposed (32k x 128n -> Bs[n][k]) ----
        #pragma unroll
        for (int s = 0; s < 16; ++s) {
            int idx = tid + s * 256;      // 0..4095
            int c = idx >> 7;             // k offset 0..31
            int t = idx & 127;            // n offset
            int k = k0 + c;
            float v = (k < 156) ? Inb[(long long)k * 2048 + n0 + t] : 0.f;
            Bs[t][c] = f2bf(v);           // exact: v in {0,1}
        }
        __syncthreads();

        bf16x8 bfr[4];
        #pragma unroll
        for (int nt = 0; nt < 4; ++nt)
            bfr[nt] = *(const bf16x8*)&Bs[wx * 64 + nt * 16 + l15][kq * 8];
        #pragma unroll
        for (int s = 0; s < 3; ++s) {
            #pragma unroll
            for (int mt = 0; mt < 4; ++mt) {
                bf16x8 afr = *(const bf16x8*)&As[s][wy * 64 + mt * 16 + l15][kq * 8];
                #pragma unroll
                for (int nt = 0; nt < 4; ++nt)
                    acc[mt][nt] = __builtin_amdgcn_mfma_f32_16x16x32_bf16(
                        afr, bfr[nt], acc[mt][nt], 0, 0, 0);
            }
        }
        __syncthreads();
    }

    // epilogue: C/D layout col=lane&15, row=(lane>>4)*4+reg
    float* Db = D1 + (long long)b * 512 * 2048;
    #pragma unroll
    for (int mt = 0; mt < 4; ++mt) {
        #pragma unroll
        for (int i = 0; i < 4; ++i) {
            int m = m0 + wy * 64 + mt * 16 + kq * 4 + i;
            #pragma unroll
            for (int nt = 0; nt < 4; ++nt) {
                int n = n0 + wx * 64 + nt * 16 + l15;
                Db[(long long)m * 2048 + n] = acc[mt][nt][i];
            }
        }
    }
}

// ---------------------------------------------------------------------------
// Branch-2 GEMM1 (MFMA, split-3 bf16), batch merged into N:
//   C[m][n] = sum_k Wl1[m][k] * InF[n][k],  M=512, N=4992, K=2048
//   InF = In viewed [32*156][2048]; output scattered to Z[b][m][c], n=b*156+c.
// Block tile 64x64, BK=64, 256 thr (4 waves, 2x2 of 32x32 wave tiles).
// ---------------------------------------------------------------------------
__global__ __launch_bounds__(256) void gemmL1_mfma(
    const float* __restrict__ Wl1,  // [512][2048]
    const float* __restrict__ InF,  // [4992][2048]
    float* __restrict__ Z)          // [32][512][156]
{
    __shared__ alignas(16) unsigned short As[3][64][72]; // [split][m][k], pad 72
    __shared__ alignas(16) unsigned short Bs[64][72];    // [n][k]

    const int n0 = blockIdx.x * 64;
    const int m0 = blockIdx.y * 64;
    const int tid  = threadIdx.x;
    const int lane = tid & 63, w = tid >> 6;
    const int wy = w >> 1, wx = w & 1;
    const int l15 = lane & 15, kq = lane >> 4;

    f32x4 acc[2][2] = {};

    const int r    = tid >> 2;            // 0..63 (row within tile)
    const int coff = (tid & 3) * 16;      // 0/16/32/48 (k offset)

    for (int k0 = 0; k0 < 2048; k0 += 64) {
        // ---- stage A (64m x 64k), split-3 on the fly ----
        {
            const float* src = Wl1 + (long long)(m0 + r) * 2048 + k0 + coff;
            #pragma unroll
            for (int i = 0; i < 16; ++i) {
                unsigned short h0, h1, h2;
                split3(src[i], h0, h1, h2);
                As[0][r][coff + i] = h0;
                As[1][r][coff + i] = h1;
                As[2][r][coff + i] = h2;
            }
        }
        // ---- stage B (64n x 64k), rows already k-contiguous ----
        {
            const float* src = InF + (long long)(n0 + r) * 2048 + k0 + coff;
            #pragma unroll
            for (int i = 0; i < 16; ++i)
                Bs[r][coff + i] = f2bf(src[i]);   // exact: {0,1}
        }
        __syncthreads();

        #pragma unroll
        for (int ks = 0; ks < 2; ++ks) {
            bf16x8 bfr[2];
            #pragma unroll
            for (int nt = 0; nt < 2; ++nt)
                bfr[nt] = *(const bf16x8*)&Bs[wx * 32 + nt * 16 + l15][ks * 32 + kq * 8];
            #pragma unroll
            for (int s = 0; s < 3; ++s) {
                #pragma unroll
                for (int mt = 0; mt < 2; ++mt) {
                    bf16x8 afr = *(const bf16x8*)&As[s][wy * 32 + mt * 16 + l15][ks * 32 + kq * 8];
                    #pragma unroll
                    for (int nt = 0; nt < 2; ++nt)
                        acc[mt][nt] = __builtin_amdgcn_mfma_f32_16x16x32_bf16(
                            afr, bfr[nt], acc[mt][nt], 0, 0, 0);
                }
            }
        }
        __syncthreads();
    }

    // epilogue: n -> (b = n/156, c = n%156), store Z[b][m][c]
    #pragma unroll
    for (int mt = 0; mt < 2; ++mt) {
        #pragma unroll
        for (int i = 0; i < 4; ++i) {
            int m = m0 + wy * 32 + mt * 16 + kq * 4 + i;
            #pragma unroll
            for (int nt = 0; nt < 2; ++nt) {
                int n = n0 + wx * 32 + nt * 16 + l15;
                int bb = n / 156, cc = n - bb * 156;
                Z[((long long)bb * 512 + m) * 156 + cc] = acc[mt][nt][i];
            }
        }
    }
}

// ---------------------------------------------------------------------------
// fp32 tiled GEMM (kept for the two small M=20 GEMMs):
//   C[b][m][n] = sum_k A[m][k] * B[b][k][n]
// ---------------------------------------------------------------------------
__global__ __launch_bounds__(256) void gemm_kernel(
    const float* __restrict__ A, const float* __restrict__ B,
    float* __restrict__ C, int M, int N, int K, int ldb,
    long long bStride, long long cStride)
{
    __shared__ float As[32][65];
    __shared__ float Bs[32][65];

    const int b  = blockIdx.z;
    const int m0 = blockIdx.y * 64;
    const int n0 = blockIdx.x * 64;
    const float* Bb = B + (long long)b * bStride;
    float* Cb = C + (long long)b * cStride;

    const int tid = threadIdx.x;
    const int tx = tid & 15;
    const int ty = tid >> 4;

    float acc[4][4];
    #pragma unroll
    for (int i = 0; i < 4; ++i)
        #pragma unroll
        for (int j = 0; j < 4; ++j) acc[i][j] = 0.f;

    for (int k0 = 0; k0 < K; k0 += 32) {
        #pragma unroll
        for (int s = 0; s < 8; ++s) {
            int idx = tid + s * 256;
            int r = idx >> 5;
            int c = idx & 31;
            int m = m0 + r, k = k0 + c;
            As[c][r] = (m < M && k < K) ? A[(long long)m * K + k] : 0.f;
        }
        #pragma unroll
        for (int s = 0; s < 8; ++s) {
            int idx = tid + s * 256;
            int rr = idx >> 6;
            int c = idx & 63;
            int k = k0 + rr, n = n0 + c;
            Bs[rr][c] = (k < K && n < N) ? Bb[(long long)k * ldb + n] : 0.f;
        }
        __syncthreads();

        #pragma unroll
        for (int kk = 0; kk < 32; ++kk) {
            float av[4], bv[4];
            #pragma unroll
            for (int i = 0; i < 4; ++i) av[i] = As[kk][ty * 4 + i];
            #pragma unroll
            for (int j = 0; j < 4; ++j) bv[j] = Bs[kk][tx * 4 + j];
            #pragma unroll
            for (int i = 0; i < 4; ++i)
                #pragma unroll
                for (int j = 0; j < 4; ++j) acc[i][j] += av[i] * bv[j];
        }
        __syncthreads();
    }

    #pragma unroll
    for (int i = 0; i < 4; ++i) {
        int m = m0 + ty * 4 + i;
        if (m >= M) continue;
        #pragma unroll
        for (int j = 0; j < 4; ++j) {
            int n = n0 + tx * 4 + j;
            if (n < N) Cb[(long long)m * N + n] = acc[i][j];
        }
    }
}

// ---------------------------------------------------------------------------
// Parallel alpha-scan + spike over T=2048 per row (in-place safe).
// ---------------------------------------------------------------------------
__global__ __launch_bounds__(256) void scan_spike_T(
    const float* __restrict__ in, float* __restrict__ out,
    int out_stride, int out_offset)
{
    const int row = blockIdx.x;
    const int tid = threadIdx.x;
    const float* x = in + (long long)row * 2048 + tid * 8;

    float v[8];
    #pragma unroll
    for (int k = 0; k < 8; ++k) v[k] = x[k];

    float y = 0.f;
    #pragma unroll
    for (int k = 0; k < 8; ++k) { y = ALPHA * y + v[k]; v[k] = y; }

    __shared__ float sc[256];
    float val = y;
    sc[tid] = val;
    float m = ALPHA8;
    for (int d = 1; d < 256; d <<= 1) {
        __syncthreads();
        float p = (tid >= d) ? sc[tid - d] : 0.f;
        __syncthreads();
        val += m * p;
        sc[tid] = val;
        m *= m;
    }
    __syncthreads();
    float carry = (tid > 0) ? sc[tid - 1] : 0.f;

    float* o = out + (long long)row * out_stride + out_offset + tid * 8;
    float ak = ALPHA;
    #pragma unroll
    for (int k = 0; k < 8; ++k) {
        float yk = v[k] + ak * carry;
        ak *= ALPHA;
        o[k] = (yk >= THETA) ? 1.0f : 0.0f;
    }
}

// ---------------------------------------------------------------------------
// Branch-2 layer-1 scan: length-156 alpha-scan in perm order + spike.
// ---------------------------------------------------------------------------
__global__ __launch_bounds__(256) void scan_spike_C_perm(
    const float* __restrict__ in, const int* __restrict__ perm,
    float* __restrict__ out, int rows)
{
    __shared__ int p[156];
    for (int i = threadIdx.x; i < 156; i += blockDim.x) p[i] = perm[i];
    __syncthreads();

    int row = blockIdx.x * blockDim.x + threadIdx.x;
    if (row >= rows) return;
    const float* x = in + (long long)row * 156;
    float* o = out + (long long)row * 156;
    float y = 0.f;
    for (int c = 0; c < 156; ++c) {
        y = ALPHA * y + x[p[c]];
        o[c] = (y >= THETA) ? 1.0f : 0.0f;
    }
}

__global__ __launch_bounds__(256) void scan_spike_C_out(
    const float* __restrict__ in, float* __restrict__ out, int rows)
{
    int row = blockIdx.x * blockDim.x + threadIdx.x;
    if (row >= rows) return;
    const float* x = in + (long long)row * 156;
    float* o = out + (long long)row * 2204 + 2048;
    float y = 0.f;
    for (int c = 0; c < 156; ++c) {
        y = ALPHA * y + x[c];
        o[c] = (y >= THETA) ? 1.0f : 0.0f;
    }
}

// ---------------------------------------------------------------------------
// B=32, C_IN=156, T=2048, HID=512, OUT=20. Output [32,20,2204].
// ---------------------------------------------------------------------------
extern "C" void kernel_launch(void* const* d_in, const int* in_sizes, int n_in,
                              void* d_out, int out_size, void* d_ws, size_t ws_size,
                              hipStream_t stream)
{
    const float* In  = (const float*)d_in[0];  // [32][156][2048]
    const float* W1  = (const float*)d_in[1];  // [512][156]
    const float* W2  = (const float*)d_in[2];  // [20][512]
    const float* Wl1 = (const float*)d_in[3];  // [512][2048]
    const float* Wl2 = (const float*)d_in[4];  // [20][512]
    const int*  perm = (const int*)d_in[5];    // [156]
    float* out = (float*)d_out;                // [32][20][2204]

    float* ws  = (float*)d_ws;
    float* D1  = ws;                     // [32][512][2048] (dead after B1-GEMM2)
    float* C2  = ws + 33554432LL;        // [32][20][2048]
    float* Z   = ws;                     // [32][512][156]  (reuses D1 region)
    float* L1  = ws + 2555904LL;         // [32][512][156]
    float* Cl2 = ws + 5111808LL;         // [32][20][156]
    // peak: 34,865,152 floats = 139.5 MB

    dim3 blk(256);

    // ---- Branch 1 ----
    gemm1_mfma<<<dim3(16, 4, 32), blk, 0, stream>>>(W1, In, D1);
    scan_spike_T<<<dim3(16384), blk, 0, stream>>>(D1, D1, 2048, 0);
    gemm_kernel<<<dim3(32, 1, 32), blk, 0, stream>>>(
        W2, D1, C2, 20, 2048, 512, 2048, 512LL * 2048, 20LL * 2048);
    scan_spike_T<<<dim3(640), blk, 0, stream>>>(C2, out, 2204, 0);

    // ---- Branch 2 ----
    gemmL1_mfma<<<dim3(78, 8), blk, 0, stream>>>(Wl1, In, Z);
    scan_spike_C_perm<<<dim3(64), blk, 0, stream>>>(Z, perm, L1, 16384);
    gemm_kernel<<<dim3(3, 1, 32), blk, 0, stream>>>(
        Wl2, L1, Cl2, 20, 156, 512, 156, 512LL * 156, 20LL * 156);
    scan_spike_C_out<<<dim3(3), blk, 0, stream>>>(Cl2, out, 640);

    (void)in_sizes; (void)n_in; (void)out_size; (void)ws_size;
}

// Round 3
// 395.068 us; speedup vs baseline: 3.0546x; 1.4291x over previous
//
#include <hip/hip_runtime.h>

// SLAYER constants
#define ALPHA  0.90483741803595952f   /* exp(-1/10) */
#define ALPHA8 0.44932896411722156f   /* exp(-0.8)  */
#define THETA  10.0f
#define BF1    ((unsigned short)0x3F80) /* 1.0f as bf16 */

typedef short   bf16x8 __attribute__((ext_vector_type(8)));
typedef float   f32x4  __attribute__((ext_vector_type(4)));
typedef unsigned short ushort4v __attribute__((ext_vector_type(4)));
typedef unsigned short ushort8v __attribute__((ext_vector_type(8)));

// RNE float -> bf16 bits
__device__ __forceinline__ unsigned short f2bf(float f) {
    unsigned int x = __float_as_uint(f);
    unsigned int r = (x + 0x7FFFu + ((x >> 16) & 1u)) >> 16;
    return (unsigned short)r;
}
__device__ __forceinline__ float bf2f(unsigned short h) {
    return __uint_as_float(((unsigned int)h) << 16);
}
// 3-way bf16 split of an fp32 weight: w ~= h0+h1+h2 (residual ~2^-26 * |w|)
__device__ __forceinline__ void split3(float w, unsigned short& h0,
                                       unsigned short& h1, unsigned short& h2) {
    h0 = f2bf(w);          float r0 = w - bf2f(h0);
    h1 = f2bf(r0);         float r1 = r0 - bf2f(h1);
    h2 = f2bf(r1);
}

// ---------------------------------------------------------------------------
// Branch-1 GEMM1 (MFMA, split-3 bf16):
//   D1[b][m][n] = sum_c W1[m][c] * In[b][c][n],  M=512, N=2048, K=156 (pad 160)
// ---------------------------------------------------------------------------
__global__ __launch_bounds__(256) void gemm1_mfma(
    const float* __restrict__ W1,   // [512][156]
    const float* __restrict__ In,   // [32][156][2048]
    float* __restrict__ D1)         // [32][512][2048]
{
    __shared__ alignas(16) unsigned short As[3][128][40];
    __shared__ alignas(16) unsigned short Bs[128][40];

    const int b  = blockIdx.z;
    const int m0 = blockIdx.y * 128;
    const int n0 = blockIdx.x * 128;
    const int tid  = threadIdx.x;
    const int lane = tid & 63, w = tid >> 6;
    const int wy = w >> 1, wx = w & 1;
    const int l15 = lane & 15, kq = lane >> 4;

    const float* Inb = In + (long long)b * 156 * 2048;

    f32x4 acc[4][4] = {};

    for (int k0 = 0; k0 < 160; k0 += 32) {
        {
            int m = tid >> 1, koff = (tid & 1) * 16;
            const float* src = W1 + (long long)(m0 + m) * 156;
            #pragma unroll
            for (int i = 0; i < 16; ++i) {
                int k = k0 + koff + i;
                float v = (k < 156) ? src[k] : 0.f;
                unsigned short h0, h1, h2;
                split3(v, h0, h1, h2);
                As[0][m][koff + i] = h0;
                As[1][m][koff + i] = h1;
                As[2][m][koff + i] = h2;
            }
        }
        #pragma unroll
        for (int s = 0; s < 16; ++s) {
            int idx = tid + s * 256;
            int c = idx >> 7;
            int t = idx & 127;
            int k = k0 + c;
            float v = (k < 156) ? Inb[(long long)k * 2048 + n0 + t] : 0.f;
            Bs[t][c] = f2bf(v);
        }
        __syncthreads();

        bf16x8 bfr[4];
        #pragma unroll
        for (int nt = 0; nt < 4; ++nt)
            bfr[nt] = *(const bf16x8*)&Bs[wx * 64 + nt * 16 + l15][kq * 8];
        #pragma unroll
        for (int s = 0; s < 3; ++s) {
            #pragma unroll
            for (int mt = 0; mt < 4; ++mt) {
                bf16x8 afr = *(const bf16x8*)&As[s][wy * 64 + mt * 16 + l15][kq * 8];
                #pragma unroll
                for (int nt = 0; nt < 4; ++nt)
                    acc[mt][nt] = __builtin_amdgcn_mfma_f32_16x16x32_bf16(
                        afr, bfr[nt], acc[mt][nt], 0, 0, 0);
            }
        }
        __syncthreads();
    }

    float* Db = D1 + (long long)b * 512 * 2048;
    #pragma unroll
    for (int mt = 0; mt < 4; ++mt) {
        #pragma unroll
        for (int i = 0; i < 4; ++i) {
            int m = m0 + wy * 64 + mt * 16 + kq * 4 + i;
            #pragma unroll
            for (int nt = 0; nt < 4; ++nt) {
                int n = n0 + wx * 64 + nt * 16 + l15;
                Db[(long long)m * 2048 + n] = acc[mt][nt][i];
            }
        }
    }
}

// ---------------------------------------------------------------------------
// Branch-2 GEMM1 (MFMA, split-3 bf16), batch merged into N:
//   C[m][n] = sum_k Wl1[m][k] * InF[n][k],  M=512, N=4992, K=2048
// ---------------------------------------------------------------------------
__global__ __launch_bounds__(256) void gemmL1_mfma(
    const float* __restrict__ Wl1,  // [512][2048]
    const float* __restrict__ InF,  // [4992][2048]
    float* __restrict__ Z)          // [32][512][156]
{
    __shared__ alignas(16) unsigned short As[3][64][72];
    __shared__ alignas(16) unsigned short Bs[64][72];

    const int n0 = blockIdx.x * 64;
    const int m0 = blockIdx.y * 64;
    const int tid  = threadIdx.x;
    const int lane = tid & 63, w = tid >> 6;
    const int wy = w >> 1, wx = w & 1;
    const int l15 = lane & 15, kq = lane >> 4;

    f32x4 acc[2][2] = {};

    const int r    = tid >> 2;
    const int coff = (tid & 3) * 16;

    for (int k0 = 0; k0 < 2048; k0 += 64) {
        {
            const float* src = Wl1 + (long long)(m0 + r) * 2048 + k0 + coff;
            #pragma unroll
            for (int i = 0; i < 16; ++i) {
                unsigned short h0, h1, h2;
                split3(src[i], h0, h1, h2);
                As[0][r][coff + i] = h0;
                As[1][r][coff + i] = h1;
                As[2][r][coff + i] = h2;
            }
        }
        {
            const float* src = InF + (long long)(n0 + r) * 2048 + k0 + coff;
            #pragma unroll
            for (int i = 0; i < 16; ++i)
                Bs[r][coff + i] = f2bf(src[i]);
        }
        __syncthreads();

        #pragma unroll
        for (int ks = 0; ks < 2; ++ks) {
            bf16x8 bfr[2];
            #pragma unroll
            for (int nt = 0; nt < 2; ++nt)
                bfr[nt] = *(const bf16x8*)&Bs[wx * 32 + nt * 16 + l15][ks * 32 + kq * 8];
            #pragma unroll
            for (int s = 0; s < 3; ++s) {
                #pragma unroll
                for (int mt = 0; mt < 2; ++mt) {
                    bf16x8 afr = *(const bf16x8*)&As[s][wy * 32 + mt * 16 + l15][ks * 32 + kq * 8];
                    #pragma unroll
                    for (int nt = 0; nt < 2; ++nt)
                        acc[mt][nt] = __builtin_amdgcn_mfma_f32_16x16x32_bf16(
                            afr, bfr[nt], acc[mt][nt], 0, 0, 0);
                }
            }
        }
        __syncthreads();
    }

    #pragma unroll
    for (int mt = 0; mt < 2; ++mt) {
        #pragma unroll
        for (int i = 0; i < 4; ++i) {
            int m = m0 + wy * 32 + mt * 16 + kq * 4 + i;
            #pragma unroll
            for (int nt = 0; nt < 2; ++nt) {
                int n = n0 + wx * 32 + nt * 16 + l15;
                int bb = n / 156, cc = n - bb * 156;
                Z[((long long)bb * 512 + m) * 156 + cc] = acc[mt][nt][i];
            }
        }
    }
}

// ---------------------------------------------------------------------------
// GEMM2 (MFMA, split-3 bf16): C[b][m][n] = sum_k A[m][k] * Bsp[b][k][n]
//   A fp32 [20][512] (M padded to 32), Bsp = bf16 spikes, row stride ldb
//   (ushorts), batch stride bStrideB (ushorts). N arbitrary.
// Block: 256 thr (4 waves), tile M=32 x N=128, BK=64. Wave w covers n in
// [w*32, w*32+32).
// ---------------------------------------------------------------------------
__global__ __launch_bounds__(256) void gemm2_mfma(
    const float* __restrict__ A,
    const unsigned short* __restrict__ Bsp,
    float* __restrict__ C,
    int N, int ldb, long long bStrideB, long long cStride)
{
    __shared__ alignas(16) unsigned short As[3][32][72];
    __shared__ alignas(16) unsigned short Bs[128][72];

    const int b  = blockIdx.z;
    const int n0 = blockIdx.x * 128;
    const int tid  = threadIdx.x;
    const int lane = tid & 63, w = tid >> 6;
    const int l15 = lane & 15, kq = lane >> 4;

    const unsigned short* Bb = Bsp + (long long)b * bStrideB;

    f32x4 acc[2][2] = {};

    for (int k0 = 0; k0 < 512; k0 += 64) {
        // ---- stage A: 32m x 64k, 8/thread ----
        {
            int m = tid >> 3, koff = (tid & 7) * 8;
            const float* src = A + (long long)m * 512 + k0 + koff;
            #pragma unroll
            for (int i = 0; i < 8; ++i) {
                float v = (m < 20) ? src[i] : 0.f;
                unsigned short h0, h1, h2;
                split3(v, h0, h1, h2);
                As[0][m][koff + i] = h0;
                As[1][m][koff + i] = h1;
                As[2][m][koff + i] = h2;
            }
        }
        // ---- stage B: 64k x 128n -> Bs[n][k]; thread covers 4k x 8n ----
        {
            int kb = (tid >> 4) * 4;       // 0,4,...,60
            int nb = (tid & 15) * 8;       // 0,8,...,120
            unsigned short rv[4][8];
            #pragma unroll
            for (int kk = 0; kk < 4; ++kk) {
                const unsigned short* src =
                    Bb + (long long)(k0 + kb + kk) * ldb + n0 + nb;
                if (n0 + nb + 8 <= N) {
                    *(ushort8v*)rv[kk] = *(const ushort8v*)src;
                } else {
                    #pragma unroll
                    for (int j = 0; j < 8; ++j)
                        rv[kk][j] = (n0 + nb + j < N) ? src[j] : 0;
                }
            }
            #pragma unroll
            for (int j = 0; j < 8; ++j) {
                ushort4v v4 = { rv[0][j], rv[1][j], rv[2][j], rv[3][j] };
                *(ushort4v*)&Bs[nb + j][kb] = v4;
            }
        }
        __syncthreads();

        #pragma unroll
        for (int ks = 0; ks < 2; ++ks) {
            bf16x8 bfr[2];
            #pragma unroll
            for (int nt = 0; nt < 2; ++nt)
                bfr[nt] = *(const bf16x8*)&Bs[w * 32 + nt * 16 + l15][ks * 32 + kq * 8];
            #pragma unroll
            for (int s = 0; s < 3; ++s) {
                #pragma unroll
                for (int mt = 0; mt < 2; ++mt) {
                    bf16x8 afr = *(const bf16x8*)&As[s][mt * 16 + l15][ks * 32 + kq * 8];
                    #pragma unroll
                    for (int nt = 0; nt < 2; ++nt)
                        acc[mt][nt] = __builtin_amdgcn_mfma_f32_16x16x32_bf16(
                            afr, bfr[nt], acc[mt][nt], 0, 0, 0);
                }
            }
        }
        __syncthreads();
    }

    float* Cb = C + (long long)b * cStride;
    #pragma unroll
    for (int mt = 0; mt < 2; ++mt) {
        #pragma unroll
        for (int i = 0; i < 4; ++i) {
            int m = mt * 16 + kq * 4 + i;
            if (m >= 20) continue;
            #pragma unroll
            for (int nt = 0; nt < 2; ++nt) {
                int n = n0 + w * 32 + nt * 16 + l15;
                if (n < N) Cb[(long long)m * N + n] = acc[mt][nt][i];
            }
        }
    }
}

// ---------------------------------------------------------------------------
// Parallel alpha-scan + spike over T=2048 per row. OutT = float (1.0/0.0) or
// ushort (bf16 1.0/0.0). In-place-safe: all reads precede all writes within
// the block, and each block touches only its own row. NO __restrict__.
// ---------------------------------------------------------------------------
template <typename OutT>
__global__ __launch_bounds__(256) void scan_spike_T(
    const float* in, OutT* out, long long out_stride, int out_offset)
{
    const int row = blockIdx.x;
    const int tid = threadIdx.x;
    const float* x = in + (long long)row * 2048 + tid * 8;

    float v[8];
    #pragma unroll
    for (int k = 0; k < 8; ++k) v[k] = x[k];

    float y = 0.f;
    #pragma unroll
    for (int k = 0; k < 8; ++k) { y = ALPHA * y + v[k]; v[k] = y; }

    __shared__ float sc[256];
    float val = y;
    sc[tid] = val;
    float m = ALPHA8;
    for (int d = 1; d < 256; d <<= 1) {
        __syncthreads();
        float p = (tid >= d) ? sc[tid - d] : 0.f;
        __syncthreads();
        val += m * p;
        sc[tid] = val;
        m *= m;
    }
    __syncthreads();
    float carry = (tid > 0) ? sc[tid - 1] : 0.f;

    OutT* o = out + (long long)row * out_stride + out_offset + tid * 8;
    float ak = ALPHA;
    OutT ovals[8];
    #pragma unroll
    for (int k = 0; k < 8; ++k) {
        float yk = v[k] + ak * carry;
        ak *= ALPHA;
        bool sp = (yk >= THETA);
        if constexpr (sizeof(OutT) == 2)
            ovals[k] = sp ? (OutT)BF1 : (OutT)0;
        else
            ovals[k] = sp ? (OutT)1.0f : (OutT)0.0f;
    }
    #pragma unroll
    for (int k = 0; k < 8; ++k) o[k] = ovals[k];
}

// ---------------------------------------------------------------------------
// Branch-2 layer-1 scan: length-156 alpha-scan in perm order + spike -> bf16.
// ---------------------------------------------------------------------------
__global__ __launch_bounds__(256) void scan_spike_C_perm(
    const float* __restrict__ in, const int* __restrict__ perm,
    unsigned short* __restrict__ out, int rows)
{
    __shared__ int p[156];
    for (int i = threadIdx.x; i < 156; i += blockDim.x) p[i] = perm[i];
    __syncthreads();

    int row = blockIdx.x * blockDim.x + threadIdx.x;
    if (row >= rows) return;
    const float* x = in + (long long)row * 156;
    unsigned short* o = out + (long long)row * 156;
    float y = 0.f;
    for (int c = 0; c < 156; ++c) {
        y = ALPHA * y + x[p[c]];
        o[c] = (y >= THETA) ? BF1 : 0;
    }
}

__global__ __launch_bounds__(256) void scan_spike_C_out(
    const float* __restrict__ in, float* __restrict__ out, int rows)
{
    int row = blockIdx.x * blockDim.x + threadIdx.x;
    if (row >= rows) return;
    const float* x = in + (long long)row * 156;
    float* o = out + (long long)row * 2204 + 2048;
    float y = 0.f;
    for (int c = 0; c < 156; ++c) {
        y = ALPHA * y + x[c];
        o[c] = (y >= THETA) ? 1.0f : 0.0f;
    }
}

// ---------------------------------------------------------------------------
// B=32, C_IN=156, T=2048, HID=512, OUT=20. Output [32,20,2204].
// ---------------------------------------------------------------------------
extern "C" void kernel_launch(void* const* d_in, const int* in_sizes, int n_in,
                              void* d_out, int out_size, void* d_ws, size_t ws_size,
                              hipStream_t stream)
{
    const float* In  = (const float*)d_in[0];  // [32][156][2048]
    const float* W1  = (const float*)d_in[1];  // [512][156]
    const float* W2  = (const float*)d_in[2];  // [20][512]
    const float* Wl1 = (const float*)d_in[3];  // [512][2048]
    const float* Wl2 = (const float*)d_in[4];  // [20][512]
    const int*  perm = (const int*)d_in[5];    // [156]
    float* out = (float*)d_out;                // [32][20][2204]

    float* ws  = (float*)d_ws;
    float* D1  = ws;                          // [32][512][2048] fp32; s1 bf16 overlaid
    unsigned short* S1 = (unsigned short*)D1; // row r at ushort offset r*4096
    float* C2  = ws + 33554432LL;             // [32][20][2048]
    float* Z   = ws + 34865152LL;             // [32][512][156]
    unsigned short* L1u = (unsigned short*)(ws + 37421056LL); // [32][512][156] bf16
    float* Cl2 = ws + 38699008LL;             // [32][20][156]
    // total 38,798,848 floats = 155.2 MB

    dim3 blk(256);

    // ---- Branch 1 ----
    gemm1_mfma<<<dim3(16, 4, 32), blk, 0, stream>>>(W1, In, D1);
    // s1 = spike(psp(D1)) -> bf16, overlaid in-place on D1 rows (stride 4096 ushorts)
    scan_spike_T<unsigned short><<<dim3(16384), blk, 0, stream>>>(D1, S1, 4096, 0);
    // C2[b][o][t] = sum_h W2[o][h] * s1[b][h][t]
    gemm2_mfma<<<dim3(16, 1, 32), blk, 0, stream>>>(
        W2, S1, C2, 2048, 4096, 512LL * 4096, 20LL * 2048);
    // spike_output -> out[..., 0:2048]
    scan_spike_T<float><<<dim3(640), blk, 0, stream>>>(C2, out, 2204, 0);

    // ---- Branch 2 ----
    gemmL1_mfma<<<dim3(78, 8), blk, 0, stream>>>(Wl1, In, Z);
    scan_spike_C_perm<<<dim3(64), blk, 0, stream>>>(Z, perm, L1u, 16384);
    gemm2_mfma<<<dim3(2, 1, 32), blk, 0, stream>>>(
        Wl2, L1u, Cl2, 156, 156, 512LL * 156, 20LL * 156);
    scan_spike_C_out<<<dim3(3), blk, 0, stream>>>(Cl2, out, 640);

    (void)in_sizes; (void)n_in; (void)out_size; (void)ws_size;
}